// Round 6
// baseline (1164.480 us; speedup 1.0000x reference)
//
#include <hip/hip_runtime.h>
#include <hip/hip_bf16.h>
#include <hip/hip_fp16.h>

// GCN 4 layers. t_pre = dinv[row]*(H @ W) via fp16 split-weight MFMA, stored fp16
// in SLICE-MAJOR layout [slice][node][16 feats] so each XCD's L2 holds one 3.2MB
// slice (blockIdx%8 -> XCD round-robin heuristic). Aggregation is slice-parallel.
// out[i] = dinv[i]*(sum_{src->i} t_pre[src] + t_pre[i]) + b ; relu (not last).

#define NNODES 100000
#define NEDGES 1600000
#define NBUCK 782          // ceil(N/128)

typedef __attribute__((ext_vector_type(8))) _Float16 f16x8;
typedef __attribute__((ext_vector_type(4))) float f32x4;

// ---------------- helpers ----------------

__device__ inline float2 h2f2(unsigned int u) {
    __half2 h = *reinterpret_cast<__half2*>(&u);
    return __half22float2(h);
}
__device__ inline unsigned int f22h2(float a, float b) {
    __half2 h = __floats2half2_rn(a, b);
    return *reinterpret_cast<unsigned int*>(&h);
}

// fp16 2-term split: x = h + l + O(2^-24 x)
__device__ inline void split_h(float x, __half& h, __half& l) {
    h = __float2half(x);
    l = __float2half(x - __half2float(h));
}

// ---------------- bucket-partition CSR build ----------------

__global__ void zero_ints(int* p, int n) {
    int i = blockIdx.x * blockDim.x + threadIdx.x;
    if (i < n) p[i] = 0;
}

__global__ __launch_bounds__(256) void hist_pass(const int* __restrict__ dst,
                                                 int* __restrict__ cnt, int e) {
    __shared__ int h[NBUCK];
    int tid = threadIdx.x;
    for (int i = tid; i < NBUCK; i += 256) h[i] = 0;
    __syncthreads();
    int base_e = blockIdx.x * 4096;
#pragma unroll
    for (int j = 0; j < 16; j++) {
        int i = base_e + j * 256 + tid;
        if (i < e) atomicAdd(&h[dst[i] >> 7], 1);
    }
    __syncthreads();
    for (int b = tid; b < NBUCK; b += 256)
        if (h[b]) atomicAdd(&cnt[b], h[b]);
}

// weight -> fp16 hi/lo fragment order.
// frag layout: [chunk c][tile t][lane l][j], k = c*32 + (l>>4)*8 + j, n = t*16 + (l&15)
__device__ inline void wfrag_one(const float* W, unsigned short* hi, unsigned short* lo,
                                 int e, int NT, int Ncols) {
    int j = e & 7;
    int l = (e >> 3) & 63;
    int t = (e >> 9) % NT;
    int c = e / (512 * NT);
    int k = c * 32 + (l >> 4) * 8 + j;
    int n = t * 16 + (l & 15);
    float x = W[k * Ncols + n];
    __half h, lw; split_h(x, h, lw);
    hi[e] = *(unsigned short*)&h;
    lo[e] = *(unsigned short*)&lw;
}

// aux: blocks 0..223 convert weights; block 224 scans bucket counts (after hist).
__global__ __launch_bounds__(256) void aux_kernel(
        const float* W1, unsigned short* hi1, unsigned short* lo1,
        const float* Wm1, unsigned short* him1, unsigned short* lom1,
        const float* Wm2, unsigned short* him2, unsigned short* lom2,
        const float* W2, unsigned short* hi2, unsigned short* lo2,
        const int* __restrict__ cnt, int* __restrict__ base, int e) {
    int blk = blockIdx.x;
    int tid = threadIdx.x;
    if (blk < 64)        { wfrag_one(W1,  hi1,  lo1,  blk * 256 + tid,         8, 128); return; }
    if (blk < 128)       { wfrag_one(Wm1, him1, lom1, (blk - 64) * 256 + tid,  8, 128); return; }
    if (blk < 192)       { wfrag_one(Wm2, him2, lom2, (blk - 128) * 256 + tid, 8, 128); return; }
    if (blk < 224)       { wfrag_one(W2,  hi2,  lo2,  (blk - 192) * 256 + tid, 4, 64);  return; }
    __shared__ int sd[256];
    int t = tid;
    int v[4]; int s = 0;
#pragma unroll
    for (int j = 0; j < 4; j++) {
        int i = t * 4 + j;
        v[j] = (i < NBUCK) ? cnt[i] : 0;
        s += v[j];
    }
    sd[t] = s; __syncthreads();
    for (int off = 1; off < 256; off <<= 1) {
        int x = (t >= off) ? sd[t - off] : 0;
        __syncthreads();
        sd[t] += x;
        __syncthreads();
    }
    int run = sd[t] - s;   // exclusive
#pragma unroll
    for (int j = 0; j < 4; j++) {
        int i = t * 4 + j;
        if (i < NBUCK) base[i] = run;
        run += v[j];
    }
    if (t == 0) base[NBUCK] = e;
}

__global__ void copy_fill(const int* __restrict__ base, int* __restrict__ fill) {
    int i = blockIdx.x * blockDim.x + threadIdx.x;
    if (i < NBUCK) fill[i] = base[i];
}

// pass 2: re-histogram per chunk, reserve ranges, scatter packed (src<<7)|(dst&127).
__global__ __launch_bounds__(256) void scatter_pass(const int* __restrict__ src,
                                                    const int* __restrict__ dst,
                                                    int* __restrict__ fill,
                                                    unsigned int* __restrict__ epart, int e) {
    __shared__ int h[NBUCK];
    int tid = threadIdx.x;
    for (int i = tid; i < NBUCK; i += 256) h[i] = 0;
    __syncthreads();
    int base_e = blockIdx.x * 4096;
#pragma unroll
    for (int j = 0; j < 16; j++) {
        int i = base_e + j * 256 + tid;
        if (i < e) atomicAdd(&h[dst[i] >> 7], 1);
    }
    __syncthreads();
    for (int b = tid; b < NBUCK; b += 256)
        if (h[b]) h[b] = atomicAdd(&fill[b], h[b]);
    __syncthreads();
#pragma unroll
    for (int j = 0; j < 16; j++) {
        int i = base_e + j * 256 + tid;
        if (i < e) {
            int d = dst[i];
            int bk = d >> 7;
            int pos = atomicAdd(&h[bk], 1);
            epart[pos] = ((unsigned int)src[i] << 7) | (unsigned int)(d & 127);
        }
    }
}

// pass 3: block per bucket -> row_ptr, dinv, col.
__global__ __launch_bounds__(256) void build_csr(const unsigned int* __restrict__ epart,
                                                 const int* __restrict__ base,
                                                 int* __restrict__ row_ptr,
                                                 int* __restrict__ col,
                                                 float* __restrict__ dinv,
                                                 int n, int e_total) {
    __shared__ int deg[128], off[128], fil[128];
    int b = blockIdx.x, tid = threadIdx.x;
    int node0 = b << 7;
    int nn = n - node0; if (nn > 128) nn = 128;
    int e0 = base[b], e1 = base[b + 1];
    int cnt = e1 - e0;

    if (tid < 128) deg[tid] = 0;
    __syncthreads();
    for (int i = tid; i < cnt; i += 256)
        atomicAdd(&deg[epart[e0 + i] & 127], 1);
    __syncthreads();
    if (tid < 128) off[tid] = deg[tid];
    __syncthreads();
    for (int o = 1; o < 128; o <<= 1) {
        int x = (tid < 128 && tid >= o) ? off[tid - o] : 0;
        __syncthreads();
        if (tid < 128) off[tid] += x;
        __syncthreads();
    }
    if (tid < 128) {
        int ex = e0 + off[tid] - deg[tid];
        fil[tid] = ex;
        if (tid < nn) {
            row_ptr[node0 + tid] = ex;
            dinv[node0 + tid] = rsqrtf((float)(deg[tid] + 1));
        }
    }
    if (b == 0 && tid == 0) row_ptr[n] = e_total;
    __syncthreads();
    for (int i = tid; i < cnt; i += 256) {
        unsigned int u = epart[e0 + i];
        int ld = (int)(u & 127);
        int pos = atomicAdd(&fil[ld], 1);
        col[pos] = (int)(u >> 7);
    }
}

// ---------------- GEMM layer 1: fp32 row-major A, fp16 2-term split both sides -------
// Output SLICED: T[(slice*nrows + row)*16 + feat], slice = col/16.

__global__ __launch_bounds__(256) void gemm_l1(const float* __restrict__ A,
                                               const unsigned short* __restrict__ gwhi,
                                               const unsigned short* __restrict__ gwlo,
                                               const float* __restrict__ dinv,
                                               __half* __restrict__ T, int nrows) {
    constexpr int NT = 8;
    constexpr int WFRAG = 4 * NT * 64 * 8;
    __shared__ __align__(16) unsigned short s_hi[WFRAG];
    __shared__ __align__(16) unsigned short s_lo[WFRAG];
    int tid = threadIdx.x;
    for (int i = tid; i < WFRAG / 8; i += 256) {
        ((uint4*)s_hi)[i] = ((const uint4*)gwhi)[i];
        ((uint4*)s_lo)[i] = ((const uint4*)gwlo)[i];
    }
    __syncthreads();

    int wave = tid >> 6, lane = tid & 63;
    int m = lane & 15, q = lane >> 4;
    long row0 = ((long)blockIdx.x * 4 + wave) * 32;
    if (row0 >= nrows) return;
    long rowa = row0 + m;
    bool hasb = (row0 + 16) < nrows;
    long rowb = hasb ? (row0 + 16 + m) : rowa;

    f32x4 acc[2][NT];
#pragma unroll
    for (int s = 0; s < 2; s++)
#pragma unroll
        for (int t = 0; t < NT; t++)
#pragma unroll
            for (int r = 0; r < 4; r++) acc[s][t][r] = 0.f;

#pragma unroll
    for (int c = 0; c < 4; c++) {
        f16x8 ah[2], al[2];
        const float* pa = A + rowa * 128 + c * 32 + q * 8;
        const float* pb = A + rowb * 128 + c * 32 + q * 8;
        float fa[8], fb[8];
        *(float4*)&fa[0] = *(const float4*)pa;
        *(float4*)&fa[4] = *(const float4*)(pa + 4);
        *(float4*)&fb[0] = *(const float4*)pb;
        *(float4*)&fb[4] = *(const float4*)(pb + 4);
#pragma unroll
        for (int i = 0; i < 8; i++) {
            __half h, l;
            split_h(fa[i], h, l); ah[0][i] = *(_Float16*)&h; al[0][i] = *(_Float16*)&l;
            split_h(fb[i], h, l); ah[1][i] = *(_Float16*)&h; al[1][i] = *(_Float16*)&l;
        }
#pragma unroll
        for (int t = 0; t < NT; t++) {
            f16x8 bhi = *(const f16x8*)(s_hi + ((c * NT + t) * 64 + lane) * 8);
            f16x8 blo = *(const f16x8*)(s_lo + ((c * NT + t) * 64 + lane) * 8);
#pragma unroll
            for (int s = 0; s < 2; s++) {
                acc[s][t] = __builtin_amdgcn_mfma_f32_16x16x32_f16(al[s], bhi, acc[s][t], 0, 0, 0);
                acc[s][t] = __builtin_amdgcn_mfma_f32_16x16x32_f16(ah[s], blo, acc[s][t], 0, 0, 0);
                acc[s][t] = __builtin_amdgcn_mfma_f32_16x16x32_f16(ah[s], bhi, acc[s][t], 0, 0, 0);
            }
        }
    }

#pragma unroll
    for (int s = 0; s < 2; s++) {
        if (s == 1 && !hasb) break;
#pragma unroll
        for (int r = 0; r < 4; r++) {
            long row = row0 + s * 16 + q * 4 + r;
            if (row < nrows) {
                float di = dinv[row];
#pragma unroll
                for (int t = 0; t < NT; t++)
                    T[((size_t)t * nrows + row) * 16 + m] = __float2half(acc[s][t][r] * di);
            }
        }
    }
}

// ---------------- GEMM layers 2-4: exact fp16 A (SLICED), fp16 2-term W, 2 MFMAs -----

template <int BN>
__global__ __launch_bounds__(256) void gemm_f16(const __half* __restrict__ A,
                                                const unsigned short* __restrict__ gwhi,
                                                const unsigned short* __restrict__ gwlo,
                                                const float* __restrict__ dinv,
                                                __half* __restrict__ T, int nrows) {
    constexpr int NT = BN / 16;
    constexpr int WFRAG = 4 * NT * 64 * 8;
    __shared__ __align__(16) unsigned short s_hi[WFRAG];
    __shared__ __align__(16) unsigned short s_lo[WFRAG];
    int tid = threadIdx.x;
    for (int i = tid; i < WFRAG / 8; i += 256) {
        ((uint4*)s_hi)[i] = ((const uint4*)gwhi)[i];
        ((uint4*)s_lo)[i] = ((const uint4*)gwlo)[i];
    }
    __syncthreads();

    int wave = tid >> 6, lane = tid & 63;
    int m = lane & 15, q = lane >> 4;
    long row0 = ((long)blockIdx.x * 4 + wave) * 32;
    if (row0 >= nrows) return;
    long rowa = row0 + m;
    bool hasb = (row0 + 16) < nrows;
    long rowb = hasb ? (row0 + 16 + m) : rowa;

    f32x4 acc[2][NT];
#pragma unroll
    for (int s = 0; s < 2; s++)
#pragma unroll
        for (int t = 0; t < NT; t++)
#pragma unroll
            for (int r = 0; r < 4; r++) acc[s][t][r] = 0.f;

#pragma unroll
    for (int c = 0; c < 4; c++) {
        // k-range c*32+q*8 .. +8 lives in input slice 2c+(q>>1), offset (q&1)*8
        int isl = 2 * c + (q >> 1);
        int ioff = (q & 1) * 8;
        f16x8 a[2];
        *(uint4*)&a[0] = *(const uint4*)(A + ((size_t)isl * nrows + rowa) * 16 + ioff);
        *(uint4*)&a[1] = *(const uint4*)(A + ((size_t)isl * nrows + rowb) * 16 + ioff);
#pragma unroll
        for (int t = 0; t < NT; t++) {
            f16x8 bhi = *(const f16x8*)(s_hi + ((c * NT + t) * 64 + lane) * 8);
            f16x8 blo = *(const f16x8*)(s_lo + ((c * NT + t) * 64 + lane) * 8);
#pragma unroll
            for (int s = 0; s < 2; s++) {
                acc[s][t] = __builtin_amdgcn_mfma_f32_16x16x32_f16(a[s], blo, acc[s][t], 0, 0, 0);
                acc[s][t] = __builtin_amdgcn_mfma_f32_16x16x32_f16(a[s], bhi, acc[s][t], 0, 0, 0);
            }
        }
    }

#pragma unroll
    for (int s = 0; s < 2; s++) {
        if (s == 1 && !hasb) break;
#pragma unroll
        for (int r = 0; r < 4; r++) {
            long row = row0 + s * 16 + q * 4 + r;
            if (row < nrows) {
                float di = dinv[row];
#pragma unroll
                for (int t = 0; t < NT; t++)
                    T[((size_t)t * nrows + row) * 16 + m] = __float2half(acc[s][t][r] * di);
            }
        }
    }
}

// ---------------- aggregation: slice-parallel, wave per (node, slice) ----------------
// lane = q*8+i: q = edge slot (8 edges/instr), i = feature-pair. Table slice (3.2MB)
// stays resident in the slice's XCD L2 (blockIdx%8 -> XCD heuristic); col/out use
// nontemporal hints so streams don't evict it.

__global__ __launch_bounds__(256) void agg128s(const __half* __restrict__ t,
                                               const int* __restrict__ row_ptr,
                                               const int* __restrict__ col,
                                               const float* __restrict__ dinv,
                                               const float* __restrict__ bias,
                                               __half* __restrict__ out, int n) {
    int wave = threadIdx.x >> 6, lane = threadIdx.x & 63;
    int slice = blockIdx.x & 7;
    int node = (blockIdx.x >> 3) * 4 + wave;
    if (node >= n) return;
    int q = lane >> 3, i = lane & 7;
    int r0 = row_ptr[node], r1 = row_ptr[node + 1];
    const unsigned int* tbl = (const unsigned int*)t + (size_t)slice * n * 8 + i;

    float s0 = 0.f, s1 = 0.f, u0 = 0.f, u1 = 0.f;
    int p = r0;
    for (; p + 16 <= r1; p += 16) {
        int c0 = __builtin_nontemporal_load(col + p + q);
        int c1 = __builtin_nontemporal_load(col + p + 8 + q);
        unsigned int v0 = tbl[(size_t)c0 * 8];
        unsigned int v1 = tbl[(size_t)c1 * 8];
        float2 f0 = h2f2(v0), f1 = h2f2(v1);
        s0 += f0.x; s1 += f0.y; u0 += f1.x; u1 += f1.y;
    }
    for (; p + 8 <= r1; p += 8) {
        int c0 = __builtin_nontemporal_load(col + p + q);
        float2 f0 = h2f2(tbl[(size_t)c0 * 8]);
        s0 += f0.x; s1 += f0.y;
    }
    if (p + q < r1) {
        int c0 = __builtin_nontemporal_load(col + p + q);
        float2 f0 = h2f2(tbl[(size_t)c0 * 8]);
        s0 += f0.x; s1 += f0.y;
    }
    s0 += u0; s1 += u1;
    s0 += __shfl_xor(s0, 8);  s1 += __shfl_xor(s1, 8);
    s0 += __shfl_xor(s0, 16); s1 += __shfl_xor(s1, 16);
    s0 += __shfl_xor(s0, 32); s1 += __shfl_xor(s1, 32);

    if (q == 0) {
        float2 own = h2f2(tbl[(size_t)node * 8]);
        float di = dinv[node];
        float2 b = *(const float2*)(bias + slice * 16 + i * 2);
        float o0 = di * (s0 + own.x) + b.x;
        float o1 = di * (s1 + own.y) + b.y;
        o0 = fmaxf(o0, 0.f); o1 = fmaxf(o1, 0.f);
        __builtin_nontemporal_store(f22h2(o0, o1),
            (unsigned int*)out + (size_t)slice * n * 8 + (size_t)node * 8 + i);
    }
}

// 64-feature final layer: 4 slices, fp32 row-major output (no relu).
__global__ __launch_bounds__(256) void agg64s(const __half* __restrict__ t,
                                              const int* __restrict__ row_ptr,
                                              const int* __restrict__ col,
                                              const float* __restrict__ dinv,
                                              const float* __restrict__ bias,
                                              float* __restrict__ out, int n) {
    int wave = threadIdx.x >> 6, lane = threadIdx.x & 63;
    int slice = blockIdx.x & 3;
    int node = (blockIdx.x >> 2) * 4 + wave;
    if (node >= n) return;
    int q = lane >> 3, i = lane & 7;
    int r0 = row_ptr[node], r1 = row_ptr[node + 1];
    const unsigned int* tbl = (const unsigned int*)t + (size_t)slice * n * 8 + i;

    float s0 = 0.f, s1 = 0.f, u0 = 0.f, u1 = 0.f;
    int p = r0;
    for (; p + 16 <= r1; p += 16) {
        int c0 = __builtin_nontemporal_load(col + p + q);
        int c1 = __builtin_nontemporal_load(col + p + 8 + q);
        unsigned int v0 = tbl[(size_t)c0 * 8];
        unsigned int v1 = tbl[(size_t)c1 * 8];
        float2 f0 = h2f2(v0), f1 = h2f2(v1);
        s0 += f0.x; s1 += f0.y; u0 += f1.x; u1 += f1.y;
    }
    for (; p + 8 <= r1; p += 8) {
        int c0 = __builtin_nontemporal_load(col + p + q);
        float2 f0 = h2f2(tbl[(size_t)c0 * 8]);
        s0 += f0.x; s1 += f0.y;
    }
    if (p + q < r1) {
        int c0 = __builtin_nontemporal_load(col + p + q);
        float2 f0 = h2f2(tbl[(size_t)c0 * 8]);
        s0 += f0.x; s1 += f0.y;
    }
    s0 += u0; s1 += u1;
    s0 += __shfl_xor(s0, 8);  s1 += __shfl_xor(s1, 8);
    s0 += __shfl_xor(s0, 16); s1 += __shfl_xor(s1, 16);
    s0 += __shfl_xor(s0, 32); s1 += __shfl_xor(s1, 32);

    if (q == 0) {
        float2 own = h2f2(tbl[(size_t)node * 8]);
        float di = dinv[node];
        float2 b = *(const float2*)(bias + slice * 16 + i * 2);
        float2 o;
        o.x = di * (s0 + own.x) + b.x;
        o.y = di * (s1 + own.y) + b.y;
        *(float2*)(out + (size_t)node * 64 + slice * 16 + i * 2) = o;
    }
}

// ---------------- launch ----------------

extern "C" void kernel_launch(void* const* d_in, const int* in_sizes, int n_in,
                              void* d_out, int out_size, void* d_ws, size_t ws_size,
                              hipStream_t stream) {
    const int N = NNODES, E = NEDGES;
    const float* x   = (const float*)d_in[0];
    const int*   ei  = (const int*)d_in[1];
    const int*   src = ei;
    const int*   dst = ei + E;
    const float* W1  = (const float*)d_in[2];
    const float* b1  = (const float*)d_in[3];
    const float* Wm1 = (const float*)d_in[4];
    const float* bm1 = (const float*)d_in[5];
    const float* Wm2 = (const float*)d_in[6];
    const float* bm2 = (const float*)d_in[7];
    const float* W2  = (const float*)d_in[8];
    const float* b2  = (const float*)d_in[9];
    float* out = (float*)d_out;

    // workspace layout (16B-aligned segments)
    int* bucket_cnt  = (int*)d_ws;                        // 784
    int* bucket_base = bucket_cnt + 784;                  // 784 (NBUCK+1 used)
    int* bucket_fill = bucket_base + 784;                 // 784
    int* row_ptr     = bucket_fill + 784;                 // N+4
    int* col         = row_ptr + (N + 4);                 // E
    unsigned int* epart = (unsigned int*)(col + E);       // E
    float* dinv  = (float*)(epart + E);                   // N
    __half* t16  = (__half*)(dinv + N);                   // N*128 halves (sliced)
    __half* bufA = t16 + (size_t)N * 128;                 // N*128 halves (sliced)
    unsigned short* whi1  = (unsigned short*)(bufA + (size_t)N * 128);
    unsigned short* wlo1  = whi1 + 16384;
    unsigned short* whiM1 = wlo1 + 16384;
    unsigned short* wloM1 = whiM1 + 16384;
    unsigned short* whiM2 = wloM1 + 16384;
    unsigned short* wloM2 = whiM2 + 16384;
    unsigned short* whi2  = wloM2 + 16384;
    unsigned short* wlo2  = whi2 + 8192;

    const int EB4 = (E + 4095) / 4096;   // 391

    zero_ints<<<4, 256, 0, stream>>>(bucket_cnt, NBUCK);
    hist_pass<<<EB4, 256, 0, stream>>>(dst, bucket_cnt, E);
    aux_kernel<<<225, 256, 0, stream>>>(W1, whi1, wlo1, Wm1, whiM1, wloM1,
                                        Wm2, whiM2, wloM2, W2, whi2, wlo2,
                                        bucket_cnt, bucket_base, E);
    copy_fill<<<4, 256, 0, stream>>>(bucket_base, bucket_fill);
    scatter_pass<<<EB4, 256, 0, stream>>>(src, dst, bucket_fill, epart, E);
    build_csr<<<NBUCK, 256, 0, stream>>>(epart, bucket_base, row_ptr, col, dinv, N, E);

    const int GB  = (N + 127) / 128;         // 32 rows/wave * 4 waves
    const int NC  = (N + 3) / 4;             // node chunks (4 nodes/block)
    const int AB8 = NC * 8;                  // slice-parallel grids
    const int AB4 = NC * 4;

    gemm_l1<<<GB, 256, 0, stream>>>(x, whi1, wlo1, dinv, t16, N);
    agg128s<<<AB8, 256, 0, stream>>>(t16, row_ptr, col, dinv, b1, bufA, N);

    gemm_f16<128><<<GB, 256, 0, stream>>>(bufA, whiM1, wloM1, dinv, t16, N);
    agg128s<<<AB8, 256, 0, stream>>>(t16, row_ptr, col, dinv, bm1, bufA, N);

    gemm_f16<128><<<GB, 256, 0, stream>>>(bufA, whiM2, wloM2, dinv, t16, N);
    agg128s<<<AB8, 256, 0, stream>>>(t16, row_ptr, col, dinv, bm2, bufA, N);

    gemm_f16<64><<<GB, 256, 0, stream>>>(bufA, whi2, wlo2, dinv, t16, N);
    agg64s<<<AB4, 256, 0, stream>>>(t16, row_ptr, col, dinv, b2, out, N);
}

// Round 8
// 883.903 us; speedup vs baseline: 1.3174x; 1.3174x over previous
//
#include <hip/hip_runtime.h>
#include <hip/hip_bf16.h>
#include <hip/hip_fp16.h>

// GCN 4 layers. t_pre = dinv[row]*(H @ W) via fp16 split-weight MFMA, stored fp16
// in SLICE-MAJOR layout [slice][node][16 feats]; each XCD's L2 holds one 3.2MB slice
// (blockIdx%NSL -> XCD round-robin). Aggregation: block = (128-node bucket, slice),
// col/row_ptr/dinv staged in LDS, wave = 32 sequential nodes, outputs flushed as
// coalesced 1KB nt stores. out[i] = dinv[i]*(sum t_pre[src] + t_pre[i]) + b; relu.

#define NNODES 100000
#define NEDGES 1600000
#define NBUCK 782          // ceil(N/128)
#define CAP 3072           // LDS col capacity per 128-node bucket (avg 2176, +19 sigma)

typedef __attribute__((ext_vector_type(8))) _Float16 f16x8;
typedef __attribute__((ext_vector_type(4))) float f32x4;
typedef __attribute__((ext_vector_type(4))) unsigned int u32x4;

// ---------------- helpers ----------------

__device__ inline float2 h2f2(unsigned int u) {
    __half2 h = *reinterpret_cast<__half2*>(&u);
    return __half22float2(h);
}
__device__ inline unsigned int f22h2(float a, float b) {
    __half2 h = __floats2half2_rn(a, b);
    return *reinterpret_cast<unsigned int*>(&h);
}

// fp16 2-term split: x = h + l + O(2^-24 x)
__device__ inline void split_h(float x, __half& h, __half& l) {
    h = __float2half(x);
    l = __float2half(x - __half2float(h));
}

// ---------------- bucket-partition CSR build ----------------

__global__ void zero_ints(int* p, int n) {
    int i = blockIdx.x * blockDim.x + threadIdx.x;
    if (i < n) p[i] = 0;
}

__global__ __launch_bounds__(256) void hist_pass(const int* __restrict__ dst,
                                                 int* __restrict__ cnt, int e) {
    __shared__ int h[NBUCK];
    int tid = threadIdx.x;
    for (int i = tid; i < NBUCK; i += 256) h[i] = 0;
    __syncthreads();
    int base_e = blockIdx.x * 4096;
#pragma unroll
    for (int j = 0; j < 16; j++) {
        int i = base_e + j * 256 + tid;
        if (i < e) atomicAdd(&h[dst[i] >> 7], 1);
    }
    __syncthreads();
    for (int b = tid; b < NBUCK; b += 256)
        if (h[b]) atomicAdd(&cnt[b], h[b]);
}

// weight -> fp16 hi/lo fragment order.
// frag layout: [chunk c][tile t][lane l][j], k = c*32 + (l>>4)*8 + j, n = t*16 + (l&15)
__device__ inline void wfrag_one(const float* W, unsigned short* hi, unsigned short* lo,
                                 int e, int NT, int Ncols) {
    int j = e & 7;
    int l = (e >> 3) & 63;
    int t = (e >> 9) % NT;
    int c = e / (512 * NT);
    int k = c * 32 + (l >> 4) * 8 + j;
    int n = t * 16 + (l & 15);
    float x = W[k * Ncols + n];
    __half h, lw; split_h(x, h, lw);
    hi[e] = *(unsigned short*)&h;
    lo[e] = *(unsigned short*)&lw;
}

// aux: blocks 0..223 convert weights; block 224 scans bucket counts (after hist).
__global__ __launch_bounds__(256) void aux_kernel(
        const float* W1, unsigned short* hi1, unsigned short* lo1,
        const float* Wm1, unsigned short* him1, unsigned short* lom1,
        const float* Wm2, unsigned short* him2, unsigned short* lom2,
        const float* W2, unsigned short* hi2, unsigned short* lo2,
        const int* __restrict__ cnt, int* __restrict__ base, int e) {
    int blk = blockIdx.x;
    int tid = threadIdx.x;
    if (blk < 64)        { wfrag_one(W1,  hi1,  lo1,  blk * 256 + tid,         8, 128); return; }
    if (blk < 128)       { wfrag_one(Wm1, him1, lom1, (blk - 64) * 256 + tid,  8, 128); return; }
    if (blk < 192)       { wfrag_one(Wm2, him2, lom2, (blk - 128) * 256 + tid, 8, 128); return; }
    if (blk < 224)       { wfrag_one(W2,  hi2,  lo2,  (blk - 192) * 256 + tid, 4, 64);  return; }
    __shared__ int sd[256];
    int t = tid;
    int v[4]; int s = 0;
#pragma unroll
    for (int j = 0; j < 4; j++) {
        int i = t * 4 + j;
        v[j] = (i < NBUCK) ? cnt[i] : 0;
        s += v[j];
    }
    sd[t] = s; __syncthreads();
    for (int off = 1; off < 256; off <<= 1) {
        int x = (t >= off) ? sd[t - off] : 0;
        __syncthreads();
        sd[t] += x;
        __syncthreads();
    }
    int run = sd[t] - s;   // exclusive
#pragma unroll
    for (int j = 0; j < 4; j++) {
        int i = t * 4 + j;
        if (i < NBUCK) base[i] = run;
        run += v[j];
    }
    if (t == 0) base[NBUCK] = e;
}

__global__ void copy_fill(const int* __restrict__ base, int* __restrict__ fill) {
    int i = blockIdx.x * blockDim.x + threadIdx.x;
    if (i < NBUCK) fill[i] = base[i];
}

// pass 2: re-histogram per chunk, reserve ranges, scatter packed (src<<7)|(dst&127).
__global__ __launch_bounds__(256) void scatter_pass(const int* __restrict__ src,
                                                    const int* __restrict__ dst,
                                                    int* __restrict__ fill,
                                                    unsigned int* __restrict__ epart, int e) {
    __shared__ int h[NBUCK];
    int tid = threadIdx.x;
    for (int i = tid; i < NBUCK; i += 256) h[i] = 0;
    __syncthreads();
    int base_e = blockIdx.x * 4096;
#pragma unroll
    for (int j = 0; j < 16; j++) {
        int i = base_e + j * 256 + tid;
        if (i < e) atomicAdd(&h[dst[i] >> 7], 1);
    }
    __syncthreads();
    for (int b = tid; b < NBUCK; b += 256)
        if (h[b]) h[b] = atomicAdd(&fill[b], h[b]);
    __syncthreads();
#pragma unroll
    for (int j = 0; j < 16; j++) {
        int i = base_e + j * 256 + tid;
        if (i < e) {
            int d = dst[i];
            int bk = d >> 7;
            int pos = atomicAdd(&h[bk], 1);
            epart[pos] = ((unsigned int)src[i] << 7) | (unsigned int)(d & 127);
        }
    }
}

// pass 3: block per bucket -> row_ptr, dinv, col.
__global__ __launch_bounds__(256) void build_csr(const unsigned int* __restrict__ epart,
                                                 const int* __restrict__ base,
                                                 int* __restrict__ row_ptr,
                                                 int* __restrict__ col,
                                                 float* __restrict__ dinv,
                                                 int n, int e_total) {
    __shared__ int deg[128], off[128], fil[128];
    int b = blockIdx.x, tid = threadIdx.x;
    int node0 = b << 7;
    int nn = n - node0; if (nn > 128) nn = 128;
    int e0 = base[b], e1 = base[b + 1];
    int cnt = e1 - e0;

    if (tid < 128) deg[tid] = 0;
    __syncthreads();
    for (int i = tid; i < cnt; i += 256)
        atomicAdd(&deg[epart[e0 + i] & 127], 1);
    __syncthreads();
    if (tid < 128) off[tid] = deg[tid];
    __syncthreads();
    for (int o = 1; o < 128; o <<= 1) {
        int x = (tid < 128 && tid >= o) ? off[tid - o] : 0;
        __syncthreads();
        if (tid < 128) off[tid] += x;
        __syncthreads();
    }
    if (tid < 128) {
        int ex = e0 + off[tid] - deg[tid];
        fil[tid] = ex;
        if (tid < nn) {
            row_ptr[node0 + tid] = ex;
            dinv[node0 + tid] = rsqrtf((float)(deg[tid] + 1));
        }
    }
    if (b == 0 && tid == 0) row_ptr[n] = e_total;
    __syncthreads();
    for (int i = tid; i < cnt; i += 256) {
        unsigned int u = epart[e0 + i];
        int ld = (int)(u & 127);
        int pos = atomicAdd(&fil[ld], 1);
        col[pos] = (int)(u >> 7);
    }
}

// ---------------- GEMM layer 1: fp32 row-major A, fp16 2-term split both sides -------
// Output SLICED: T[(slice*nrows + row)*16 + feat].

__global__ __launch_bounds__(256) void gemm_l1(const float* __restrict__ A,
                                               const unsigned short* __restrict__ gwhi,
                                               const unsigned short* __restrict__ gwlo,
                                               const float* __restrict__ dinv,
                                               __half* __restrict__ T, int nrows) {
    constexpr int NT = 8;
    constexpr int WFRAG = 4 * NT * 64 * 8;
    __shared__ __align__(16) unsigned short s_hi[WFRAG];
    __shared__ __align__(16) unsigned short s_lo[WFRAG];
    int tid = threadIdx.x;
    for (int i = tid; i < WFRAG / 8; i += 256) {
        ((uint4*)s_hi)[i] = ((const uint4*)gwhi)[i];
        ((uint4*)s_lo)[i] = ((const uint4*)gwlo)[i];
    }
    __syncthreads();

    int wave = tid >> 6, lane = tid & 63;
    int m = lane & 15, q = lane >> 4;
    long row0 = ((long)blockIdx.x * 4 + wave) * 32;
    if (row0 >= nrows) return;
    long rowa = row0 + m;
    bool hasb = (row0 + 16) < nrows;
    long rowb = hasb ? (row0 + 16 + m) : rowa;

    f32x4 acc[2][NT];
#pragma unroll
    for (int s = 0; s < 2; s++)
#pragma unroll
        for (int t = 0; t < NT; t++)
#pragma unroll
            for (int r = 0; r < 4; r++) acc[s][t][r] = 0.f;

#pragma unroll
    for (int c = 0; c < 4; c++) {
        f16x8 ah[2], al[2];
        const float* pa = A + rowa * 128 + c * 32 + q * 8;
        const float* pb = A + rowb * 128 + c * 32 + q * 8;
        float fa[8], fb[8];
        *(float4*)&fa[0] = *(const float4*)pa;
        *(float4*)&fa[4] = *(const float4*)(pa + 4);
        *(float4*)&fb[0] = *(const float4*)pb;
        *(float4*)&fb[4] = *(const float4*)(pb + 4);
#pragma unroll
        for (int i = 0; i < 8; i++) {
            __half h, l;
            split_h(fa[i], h, l); ah[0][i] = *(_Float16*)&h; al[0][i] = *(_Float16*)&l;
            split_h(fb[i], h, l); ah[1][i] = *(_Float16*)&h; al[1][i] = *(_Float16*)&l;
        }
#pragma unroll
        for (int t = 0; t < NT; t++) {
            f16x8 bhi = *(const f16x8*)(s_hi + ((c * NT + t) * 64 + lane) * 8);
            f16x8 blo = *(const f16x8*)(s_lo + ((c * NT + t) * 64 + lane) * 8);
#pragma unroll
            for (int s = 0; s < 2; s++) {
                acc[s][t] = __builtin_amdgcn_mfma_f32_16x16x32_f16(al[s], bhi, acc[s][t], 0, 0, 0);
                acc[s][t] = __builtin_amdgcn_mfma_f32_16x16x32_f16(ah[s], blo, acc[s][t], 0, 0, 0);
                acc[s][t] = __builtin_amdgcn_mfma_f32_16x16x32_f16(ah[s], bhi, acc[s][t], 0, 0, 0);
            }
        }
    }

#pragma unroll
    for (int s = 0; s < 2; s++) {
        if (s == 1 && !hasb) break;
#pragma unroll
        for (int r = 0; r < 4; r++) {
            long row = row0 + s * 16 + q * 4 + r;
            if (row < nrows) {
                float di = dinv[row];
#pragma unroll
                for (int t = 0; t < NT; t++)
                    T[((size_t)t * nrows + row) * 16 + m] = __float2half(acc[s][t][r] * di);
            }
        }
    }
}

// ---------------- GEMM layers 2-4: exact fp16 A (SLICED), fp16 2-term W, 2 MFMAs -----

template <int BN>
__global__ __launch_bounds__(256) void gemm_f16(const __half* __restrict__ A,
                                                const unsigned short* __restrict__ gwhi,
                                                const unsigned short* __restrict__ gwlo,
                                                const float* __restrict__ dinv,
                                                __half* __restrict__ T, int nrows) {
    constexpr int NT = BN / 16;
    constexpr int WFRAG = 4 * NT * 64 * 8;
    __shared__ __align__(16) unsigned short s_hi[WFRAG];
    __shared__ __align__(16) unsigned short s_lo[WFRAG];
    int tid = threadIdx.x;
    for (int i = tid; i < WFRAG / 8; i += 256) {
        ((uint4*)s_hi)[i] = ((const uint4*)gwhi)[i];
        ((uint4*)s_lo)[i] = ((const uint4*)gwlo)[i];
    }
    __syncthreads();

    int wave = tid >> 6, lane = tid & 63;
    int m = lane & 15, q = lane >> 4;
    long row0 = ((long)blockIdx.x * 4 + wave) * 32;
    if (row0 >= nrows) return;
    long rowa = row0 + m;
    bool hasb = (row0 + 16) < nrows;
    long rowb = hasb ? (row0 + 16 + m) : rowa;

    f32x4 acc[2][NT];
#pragma unroll
    for (int s = 0; s < 2; s++)
#pragma unroll
        for (int t = 0; t < NT; t++)
#pragma unroll
            for (int r = 0; r < 4; r++) acc[s][t][r] = 0.f;

#pragma unroll
    for (int c = 0; c < 4; c++) {
        int isl = 2 * c + (q >> 1);
        int ioff = (q & 1) * 8;
        f16x8 a[2];
        *(uint4*)&a[0] = *(const uint4*)(A + ((size_t)isl * nrows + rowa) * 16 + ioff);
        *(uint4*)&a[1] = *(const uint4*)(A + ((size_t)isl * nrows + rowb) * 16 + ioff);
#pragma unroll
        for (int t = 0; t < NT; t++) {
            f16x8 bhi = *(const f16x8*)(s_hi + ((c * NT + t) * 64 + lane) * 8);
            f16x8 blo = *(const f16x8*)(s_lo + ((c * NT + t) * 64 + lane) * 8);
#pragma unroll
            for (int s = 0; s < 2; s++) {
                acc[s][t] = __builtin_amdgcn_mfma_f32_16x16x32_f16(a[s], blo, acc[s][t], 0, 0, 0);
                acc[s][t] = __builtin_amdgcn_mfma_f32_16x16x32_f16(a[s], bhi, acc[s][t], 0, 0, 0);
            }
        }
    }

#pragma unroll
    for (int s = 0; s < 2; s++) {
        if (s == 1 && !hasb) break;
#pragma unroll
        for (int r = 0; r < 4; r++) {
            long row = row0 + s * 16 + q * 4 + r;
            if (row < nrows) {
                float di = dinv[row];
#pragma unroll
                for (int t = 0; t < NT; t++)
                    T[((size_t)t * nrows + row) * 16 + m] = __float2half(acc[s][t][r] * di);
            }
        }
    }
}

// ---------------- aggregation: block = (128-node bucket, slice) ----------------------
// lane = (q, i): q = lane>>2 edge slot (16), i = lane&3 feature-quad (uint2 = 8B).
// col/row_ptr/dinv staged in LDS; wave = 32 sequential nodes; coalesced nt flush.

__global__ __launch_bounds__(256) void agg128b(const __half* __restrict__ t,
                                               const int* __restrict__ row_ptr,
                                               const int* __restrict__ col,
                                               const float* __restrict__ dinv,
                                               const float* __restrict__ bias,
                                               __half* __restrict__ out, int n) {
    __shared__ int scol[CAP];
    __shared__ int srp[129];
    __shared__ float sdin[128];
    __shared__ unsigned int sout[1024];
    int tid = threadIdx.x;
    int slice = blockIdx.x & 7;
    int chunk = blockIdx.x >> 3;
    int node0 = chunk << 7;

    if (tid < 129) {
        int nd = node0 + tid; if (nd > n) nd = n;
        srp[tid] = row_ptr[nd];
    }
    if (tid < 128) {
        int nd = node0 + tid;
        sdin[tid] = (nd < n) ? dinv[nd] : 0.f;
    }
    __syncthreads();
    int e0 = srp[0];
    int cnt = srp[128] - e0; if (cnt > CAP) cnt = CAP;
    for (int k = tid; k < cnt; k += 256)
        scol[k] = __builtin_nontemporal_load(col + e0 + k);
    __syncthreads();

    int wave = tid >> 6, lane = tid & 63;
    int q = lane >> 2, i = lane & 3;
    const uint2* tbl = (const uint2*)t + (size_t)slice * n * 4;

    for (int tt = 0; tt < 32; tt++) {
        int ln = (wave << 5) + tt;
        int node = node0 + ln;
        int r0 = srp[ln], r1 = srp[ln + 1];    // node >= n -> r0 == r1
        float a0 = 0.f, a1 = 0.f, a2 = 0.f, a3 = 0.f;
        for (int p = r0; p < r1; p += 16) {
            int idx = p + q;
            bool v = idx < r1;
            int li = idx - e0;
            int c;
            if (v) c = (li < CAP) ? scol[li] : __builtin_nontemporal_load(col + idx);
            else   c = node;
            uint2 g = tbl[(size_t)c * 4 + i];
            float2 f0 = h2f2(g.x), f1 = h2f2(g.y);
            float mk = v ? 1.f : 0.f;
            a0 = fmaf(mk, f0.x, a0); a1 = fmaf(mk, f0.y, a1);
            a2 = fmaf(mk, f1.x, a2); a3 = fmaf(mk, f1.y, a3);
        }
#pragma unroll
        for (int st = 4; st < 64; st <<= 1) {
            a0 += __shfl_xor(a0, st); a1 += __shfl_xor(a1, st);
            a2 += __shfl_xor(a2, st); a3 += __shfl_xor(a3, st);
        }
        if (q == 0 && node < n) {
            uint2 own = tbl[(size_t)node * 4 + i];
            float2 o0 = h2f2(own.x), o1 = h2f2(own.y);
            float di = sdin[ln];
            float4 b = ((const float4*)bias)[slice * 4 + i];
            float r0v = fmaxf(fmaf(di, a0 + o0.x, b.x), 0.f);
            float r1v = fmaxf(fmaf(di, a1 + o0.y, b.y), 0.f);
            float r2v = fmaxf(fmaf(di, a2 + o1.x, b.z), 0.f);
            float r3v = fmaxf(fmaf(di, a3 + o1.y, b.w), 0.f);
            sout[(wave << 8) + (tt << 3) + (i << 1)]     = f22h2(r0v, r1v);
            sout[(wave << 8) + (tt << 3) + (i << 1) + 1] = f22h2(r2v, r3v);
        }
    }
    __syncthreads();
    // coalesced flush: wave's 32 nodes = 1024B contiguous in slice-major out
    int valid = n - (node0 + (wave << 5));
    if (valid > 32) valid = 32;
    if (valid > 0 && lane * 4 < valid * 8) {
        u32x4 v = *(const u32x4*)&sout[(wave << 8) + (lane << 2)];
        unsigned int* op = (unsigned int*)out + (size_t)slice * n * 8 +
                           (size_t)(node0 + (wave << 5)) * 8 + (lane << 2);
        __builtin_nontemporal_store(v, (u32x4*)op);
    }
}

// 64-feature final layer: 4 slices, fp32 row-major out (no relu); per-node 64B line.
__global__ __launch_bounds__(256) void agg64b(const __half* __restrict__ t,
                                              const int* __restrict__ row_ptr,
                                              const int* __restrict__ col,
                                              const float* __restrict__ dinv,
                                              const float* __restrict__ bias,
                                              float* __restrict__ out, int n) {
    __shared__ int scol[CAP];
    __shared__ int srp[129];
    __shared__ float sdin[128];
    int tid = threadIdx.x;
    int slice = blockIdx.x & 3;
    int chunk = blockIdx.x >> 2;
    int node0 = chunk << 7;

    if (tid < 129) {
        int nd = node0 + tid; if (nd > n) nd = n;
        srp[tid] = row_ptr[nd];
    }
    if (tid < 128) {
        int nd = node0 + tid;
        sdin[tid] = (nd < n) ? dinv[nd] : 0.f;
    }
    __syncthreads();
    int e0 = srp[0];
    int cnt = srp[128] - e0; if (cnt > CAP) cnt = CAP;
    for (int k = tid; k < cnt; k += 256)
        scol[k] = __builtin_nontemporal_load(col + e0 + k);
    __syncthreads();

    int wave = tid >> 6, lane = tid & 63;
    int q = lane >> 2, i = lane & 3;
    const uint2* tbl = (const uint2*)t + (size_t)slice * n * 4;

    for (int tt = 0; tt < 32; tt++) {
        int ln = (wave << 5) + tt;
        int node = node0 + ln;
        int r0 = srp[ln], r1 = srp[ln + 1];
        float a0 = 0.f, a1 = 0.f, a2 = 0.f, a3 = 0.f;
        for (int p = r0; p < r1; p += 16) {
            int idx = p + q;
            bool v = idx < r1;
            int li = idx - e0;
            int c;
            if (v) c = (li < CAP) ? scol[li] : __builtin_nontemporal_load(col + idx);
            else   c = node;
            uint2 g = tbl[(size_t)c * 4 + i];
            float2 f0 = h2f2(g.x), f1 = h2f2(g.y);
            float mk = v ? 1.f : 0.f;
            a0 = fmaf(mk, f0.x, a0); a1 = fmaf(mk, f0.y, a1);
            a2 = fmaf(mk, f1.x, a2); a3 = fmaf(mk, f1.y, a3);
        }
#pragma unroll
        for (int st = 4; st < 64; st <<= 1) {
            a0 += __shfl_xor(a0, st); a1 += __shfl_xor(a1, st);
            a2 += __shfl_xor(a2, st); a3 += __shfl_xor(a3, st);
        }
        if (q == 0 && node < n) {
            uint2 own = tbl[(size_t)node * 4 + i];
            float2 o0 = h2f2(own.x), o1 = h2f2(own.y);
            float di = sdin[ln];
            float4 b = ((const float4*)bias)[slice * 4 + i];
            float4 o;
            o.x = fmaf(di, a0 + o0.x, b.x);
            o.y = fmaf(di, a1 + o0.y, b.y);
            o.z = fmaf(di, a2 + o1.x, b.z);
            o.w = fmaf(di, a3 + o1.y, b.w);
            *(float4*)(out + (size_t)node * 64 + slice * 16 + i * 4) = o;
        }
    }
}

// ---------------- launch ----------------

extern "C" void kernel_launch(void* const* d_in, const int* in_sizes, int n_in,
                              void* d_out, int out_size, void* d_ws, size_t ws_size,
                              hipStream_t stream) {
    const int N = NNODES, E = NEDGES;
    const float* x   = (const float*)d_in[0];
    const int*   ei  = (const int*)d_in[1];
    const int*   src = ei;
    const int*   dst = ei + E;
    const float* W1  = (const float*)d_in[2];
    const float* b1  = (const float*)d_in[3];
    const float* Wm1 = (const float*)d_in[4];
    const float* bm1 = (const float*)d_in[5];
    const float* Wm2 = (const float*)d_in[6];
    const float* bm2 = (const float*)d_in[7];
    const float* W2  = (const float*)d_in[8];
    const float* b2  = (const float*)d_in[9];
    float* out = (float*)d_out;

    // workspace layout (16B-aligned segments)
    int* bucket_cnt  = (int*)d_ws;                        // 784
    int* bucket_base = bucket_cnt + 784;                  // 784 (NBUCK+1 used)
    int* bucket_fill = bucket_base + 784;                 // 784
    int* row_ptr     = bucket_fill + 784;                 // N+4
    int* col         = row_ptr + (N + 4);                 // E
    unsigned int* epart = (unsigned int*)(col + E);       // E
    float* dinv  = (float*)(epart + E);                   // N
    __half* t16  = (__half*)(dinv + N);                   // N*128 halves (sliced)
    __half* bufA = t16 + (size_t)N * 128;                 // N*128 halves (sliced)
    unsigned short* whi1  = (unsigned short*)(bufA + (size_t)N * 128);
    unsigned short* wlo1  = whi1 + 16384;
    unsigned short* whiM1 = wlo1 + 16384;
    unsigned short* wloM1 = whiM1 + 16384;
    unsigned short* whiM2 = wloM1 + 16384;
    unsigned short* wloM2 = whiM2 + 16384;
    unsigned short* whi2  = wloM2 + 16384;
    unsigned short* wlo2  = whi2 + 8192;

    const int EB4 = (E + 4095) / 4096;   // 391

    zero_ints<<<4, 256, 0, stream>>>(bucket_cnt, NBUCK);
    hist_pass<<<EB4, 256, 0, stream>>>(dst, bucket_cnt, E);
    aux_kernel<<<225, 256, 0, stream>>>(W1, whi1, wlo1, Wm1, whiM1, wloM1,
                                        Wm2, whiM2, wloM2, W2, whi2, wlo2,
                                        bucket_cnt, bucket_base, E);
    copy_fill<<<4, 256, 0, stream>>>(bucket_base, bucket_fill);
    scatter_pass<<<EB4, 256, 0, stream>>>(src, dst, bucket_fill, epart, E);
    build_csr<<<NBUCK, 256, 0, stream>>>(epart, bucket_base, row_ptr, col, dinv, N, E);

    const int GB  = (N + 127) / 128;     // gemm: 32 rows/wave * 4 waves
    const int AB8 = NBUCK * 8;           // agg blocks: bucket x slice
    const int AB4 = NBUCK * 4;

    gemm_l1<<<GB, 256, 0, stream>>>(x, whi1, wlo1, dinv, t16, N);
    agg128b<<<AB8, 256, 0, stream>>>(t16, row_ptr, col, dinv, b1, bufA, N);

    gemm_f16<128><<<GB, 256, 0, stream>>>(bufA, whiM1, wloM1, dinv, t16, N);
    agg128b<<<AB8, 256, 0, stream>>>(t16, row_ptr, col, dinv, bm1, bufA, N);

    gemm_f16<128><<<GB, 256, 0, stream>>>(bufA, whiM2, wloM2, dinv, t16, N);
    agg128b<<<AB8, 256, 0, stream>>>(t16, row_ptr, col, dinv, bm2, bufA, N);

    gemm_f16<64><<<GB, 256, 0, stream>>>(bufA, whi2, wlo2, dinv, t16, N);
    agg64b<<<AB4, 256, 0, stream>>>(t16, row_ptr, col, dinv, b2, out, N);
}

// Round 9
// 540.570 us; speedup vs baseline: 2.1542x; 1.6351x over previous
//
#include <hip/hip_runtime.h>
#include <hip/hip_bf16.h>
#include <hip/hip_fp16.h>

// GCN 4 layers. t_pre = dinv[row]*(H @ W) via fp16 split-weight MFMA, stored fp16
// row-major. out[i] = dinv[i]*(sum_{src->i} t_pre[src] + t_pre[i]) + b ; relu (not last).
// CSR via bucket partition (dst>>7). Agg: wave/node, quarter-wave = full 256B row,
// uniform masked 32-edge loop = 8 uint4 gathers in flight.

#define NNODES 100000
#define NEDGES 1600000
#define NBUCK 782          // ceil(N/128)

typedef __attribute__((ext_vector_type(8))) _Float16 f16x8;
typedef __attribute__((ext_vector_type(4))) float f32x4;

// ---------------- helpers ----------------

__device__ inline float2 h2f2(unsigned int u) {
    __half2 h = *reinterpret_cast<__half2*>(&u);
    return __half22float2(h);
}
__device__ inline unsigned int f22h2(float a, float b) {
    __half2 h = __floats2half2_rn(a, b);
    return *reinterpret_cast<unsigned int*>(&h);
}

// fp16 2-term split: x = h + l + O(2^-24 x)
__device__ inline void split_h(float x, __half& h, __half& l) {
    h = __float2half(x);
    l = __float2half(x - __half2float(h));
}

__device__ inline void accm8(float* a, uint4 v, float m) {
    float2 f0 = h2f2(v.x), f1 = h2f2(v.y), f2 = h2f2(v.z), f3 = h2f2(v.w);
    a[0] = fmaf(m, f0.x, a[0]); a[1] = fmaf(m, f0.y, a[1]);
    a[2] = fmaf(m, f1.x, a[2]); a[3] = fmaf(m, f1.y, a[3]);
    a[4] = fmaf(m, f2.x, a[4]); a[5] = fmaf(m, f2.y, a[5]);
    a[6] = fmaf(m, f3.x, a[6]); a[7] = fmaf(m, f3.y, a[7]);
}
__device__ inline void accm4(float* a, uint2 v, float m) {
    float2 f0 = h2f2(v.x), f1 = h2f2(v.y);
    a[0] = fmaf(m, f0.x, a[0]); a[1] = fmaf(m, f0.y, a[1]);
    a[2] = fmaf(m, f1.x, a[2]); a[3] = fmaf(m, f1.y, a[3]);
}

// ---------------- bucket-partition CSR build ----------------

__global__ void zero_ints(int* p, int n) {
    int i = blockIdx.x * blockDim.x + threadIdx.x;
    if (i < n) p[i] = 0;
}

__global__ __launch_bounds__(256) void hist_pass(const int* __restrict__ dst,
                                                 int* __restrict__ cnt, int e) {
    __shared__ int h[NBUCK];
    int tid = threadIdx.x;
    for (int i = tid; i < NBUCK; i += 256) h[i] = 0;
    __syncthreads();
    int base_e = blockIdx.x * 4096;
#pragma unroll
    for (int j = 0; j < 16; j++) {
        int i = base_e + j * 256 + tid;
        if (i < e) atomicAdd(&h[dst[i] >> 7], 1);
    }
    __syncthreads();
    for (int b = tid; b < NBUCK; b += 256)
        if (h[b]) atomicAdd(&cnt[b], h[b]);
}

// weight -> fp16 hi/lo fragment order.
// frag layout: [chunk c][tile t][lane l][j], k = c*32 + (l>>4)*8 + j, n = t*16 + (l&15)
__device__ inline void wfrag_one(const float* W, unsigned short* hi, unsigned short* lo,
                                 int e, int NT, int Ncols) {
    int j = e & 7;
    int l = (e >> 3) & 63;
    int t = (e >> 9) % NT;
    int c = e / (512 * NT);
    int k = c * 32 + (l >> 4) * 8 + j;
    int n = t * 16 + (l & 15);
    float x = W[k * Ncols + n];
    __half h, lw; split_h(x, h, lw);
    hi[e] = *(unsigned short*)&h;
    lo[e] = *(unsigned short*)&lw;
}

// aux: blocks 0..223 convert weights; block 224 scans bucket counts (after hist).
__global__ __launch_bounds__(256) void aux_kernel(
        const float* W1, unsigned short* hi1, unsigned short* lo1,
        const float* Wm1, unsigned short* him1, unsigned short* lom1,
        const float* Wm2, unsigned short* him2, unsigned short* lom2,
        const float* W2, unsigned short* hi2, unsigned short* lo2,
        const int* __restrict__ cnt, int* __restrict__ base, int e) {
    int blk = blockIdx.x;
    int tid = threadIdx.x;
    if (blk < 64)        { wfrag_one(W1,  hi1,  lo1,  blk * 256 + tid,         8, 128); return; }
    if (blk < 128)       { wfrag_one(Wm1, him1, lom1, (blk - 64) * 256 + tid,  8, 128); return; }
    if (blk < 192)       { wfrag_one(Wm2, him2, lom2, (blk - 128) * 256 + tid, 8, 128); return; }
    if (blk < 224)       { wfrag_one(W2,  hi2,  lo2,  (blk - 192) * 256 + tid, 4, 64);  return; }
    __shared__ int sd[256];
    int t = tid;
    int v[4]; int s = 0;
#pragma unroll
    for (int j = 0; j < 4; j++) {
        int i = t * 4 + j;
        v[j] = (i < NBUCK) ? cnt[i] : 0;
        s += v[j];
    }
    sd[t] = s; __syncthreads();
    for (int off = 1; off < 256; off <<= 1) {
        int x = (t >= off) ? sd[t - off] : 0;
        __syncthreads();
        sd[t] += x;
        __syncthreads();
    }
    int run = sd[t] - s;   // exclusive
#pragma unroll
    for (int j = 0; j < 4; j++) {
        int i = t * 4 + j;
        if (i < NBUCK) base[i] = run;
        run += v[j];
    }
    if (t == 0) base[NBUCK] = e;
}

__global__ void copy_fill(const int* __restrict__ base, int* __restrict__ fill) {
    int i = blockIdx.x * blockDim.x + threadIdx.x;
    if (i < NBUCK) fill[i] = base[i];
}

// pass 2: re-histogram per chunk, reserve ranges, scatter packed (src<<7)|(dst&127).
__global__ __launch_bounds__(256) void scatter_pass(const int* __restrict__ src,
                                                    const int* __restrict__ dst,
                                                    int* __restrict__ fill,
                                                    unsigned int* __restrict__ epart, int e) {
    __shared__ int h[NBUCK];
    int tid = threadIdx.x;
    for (int i = tid; i < NBUCK; i += 256) h[i] = 0;
    __syncthreads();
    int base_e = blockIdx.x * 4096;
#pragma unroll
    for (int j = 0; j < 16; j++) {
        int i = base_e + j * 256 + tid;
        if (i < e) atomicAdd(&h[dst[i] >> 7], 1);
    }
    __syncthreads();
    for (int b = tid; b < NBUCK; b += 256)
        if (h[b]) h[b] = atomicAdd(&fill[b], h[b]);
    __syncthreads();
#pragma unroll
    for (int j = 0; j < 16; j++) {
        int i = base_e + j * 256 + tid;
        if (i < e) {
            int d = dst[i];
            int bk = d >> 7;
            int pos = atomicAdd(&h[bk], 1);
            epart[pos] = ((unsigned int)src[i] << 7) | (unsigned int)(d & 127);
        }
    }
}

// pass 3: block per bucket -> row_ptr, dinv, col.
__global__ __launch_bounds__(256) void build_csr(const unsigned int* __restrict__ epart,
                                                 const int* __restrict__ base,
                                                 int* __restrict__ row_ptr,
                                                 int* __restrict__ col,
                                                 float* __restrict__ dinv,
                                                 int n, int e_total) {
    __shared__ int deg[128], off[128], fil[128];
    int b = blockIdx.x, tid = threadIdx.x;
    int node0 = b << 7;
    int nn = n - node0; if (nn > 128) nn = 128;
    int e0 = base[b], e1 = base[b + 1];
    int cnt = e1 - e0;

    if (tid < 128) deg[tid] = 0;
    __syncthreads();
    for (int i = tid; i < cnt; i += 256)
        atomicAdd(&deg[epart[e0 + i] & 127], 1);
    __syncthreads();
    if (tid < 128) off[tid] = deg[tid];
    __syncthreads();
    for (int o = 1; o < 128; o <<= 1) {
        int x = (tid < 128 && tid >= o) ? off[tid - o] : 0;
        __syncthreads();
        if (tid < 128) off[tid] += x;
        __syncthreads();
    }
    if (tid < 128) {
        int ex = e0 + off[tid] - deg[tid];
        fil[tid] = ex;
        if (tid < nn) {
            row_ptr[node0 + tid] = ex;
            dinv[node0 + tid] = rsqrtf((float)(deg[tid] + 1));
        }
    }
    if (b == 0 && tid == 0) row_ptr[n] = e_total;
    __syncthreads();
    for (int i = tid; i < cnt; i += 256) {
        unsigned int u = epart[e0 + i];
        int ld = (int)(u & 127);
        int pos = atomicAdd(&fil[ld], 1);
        col[pos] = (int)(u >> 7);
    }
}

// ---------------- GEMM layer 1: fp32 A, fp16 2-term split both sides, 3 MFMAs --------

__global__ __launch_bounds__(256) void gemm_l1(const float* __restrict__ A,
                                               const unsigned short* __restrict__ gwhi,
                                               const unsigned short* __restrict__ gwlo,
                                               const float* __restrict__ dinv,
                                               __half* __restrict__ T, int nrows) {
    constexpr int NT = 8, BN = 128;
    constexpr int WFRAG = 4 * NT * 64 * 8;
    __shared__ __align__(16) unsigned short s_hi[WFRAG];
    __shared__ __align__(16) unsigned short s_lo[WFRAG];
    int tid = threadIdx.x;
    for (int i = tid; i < WFRAG / 8; i += 256) {
        ((uint4*)s_hi)[i] = ((const uint4*)gwhi)[i];
        ((uint4*)s_lo)[i] = ((const uint4*)gwlo)[i];
    }
    __syncthreads();

    int wave = tid >> 6, lane = tid & 63;
    int m = lane & 15, q = lane >> 4;
    long row0 = ((long)blockIdx.x * 4 + wave) * 32;
    if (row0 >= nrows) return;
    long rowa = row0 + m;
    bool hasb = (row0 + 16) < nrows;
    long rowb = hasb ? (row0 + 16 + m) : rowa;

    f32x4 acc[2][NT];
#pragma unroll
    for (int s = 0; s < 2; s++)
#pragma unroll
        for (int t = 0; t < NT; t++)
#pragma unroll
            for (int r = 0; r < 4; r++) acc[s][t][r] = 0.f;

#pragma unroll
    for (int c = 0; c < 4; c++) {
        f16x8 ah[2], al[2];
        const float* pa = A + rowa * 128 + c * 32 + q * 8;
        const float* pb = A + rowb * 128 + c * 32 + q * 8;
        float fa[8], fb[8];
        *(float4*)&fa[0] = *(const float4*)pa;
        *(float4*)&fa[4] = *(const float4*)(pa + 4);
        *(float4*)&fb[0] = *(const float4*)pb;
        *(float4*)&fb[4] = *(const float4*)(pb + 4);
#pragma unroll
        for (int i = 0; i < 8; i++) {
            __half h, l;
            split_h(fa[i], h, l); ah[0][i] = *(_Float16*)&h; al[0][i] = *(_Float16*)&l;
            split_h(fb[i], h, l); ah[1][i] = *(_Float16*)&h; al[1][i] = *(_Float16*)&l;
        }
#pragma unroll
        for (int t = 0; t < NT; t++) {
            f16x8 bhi = *(const f16x8*)(s_hi + ((c * NT + t) * 64 + lane) * 8);
            f16x8 blo = *(const f16x8*)(s_lo + ((c * NT + t) * 64 + lane) * 8);
#pragma unroll
            for (int s = 0; s < 2; s++) {
                acc[s][t] = __builtin_amdgcn_mfma_f32_16x16x32_f16(al[s], bhi, acc[s][t], 0, 0, 0);
                acc[s][t] = __builtin_amdgcn_mfma_f32_16x16x32_f16(ah[s], blo, acc[s][t], 0, 0, 0);
                acc[s][t] = __builtin_amdgcn_mfma_f32_16x16x32_f16(ah[s], bhi, acc[s][t], 0, 0, 0);
            }
        }
    }

#pragma unroll
    for (int s = 0; s < 2; s++) {
        if (s == 1 && !hasb) break;
#pragma unroll
        for (int r = 0; r < 4; r++) {
            long row = row0 + s * 16 + q * 4 + r;
            if (row < nrows) {
                float di = dinv[row];
#pragma unroll
                for (int t = 0; t < NT; t++)
                    T[row * BN + t * 16 + m] = __float2half(acc[s][t][r] * di);
            }
        }
    }
}

// ---------------- GEMM layers 2-4: exact fp16 A, fp16 2-term W, 2 MFMAs --------------

template <int BN>
__global__ __launch_bounds__(256) void gemm_f16(const __half* __restrict__ A,
                                                const unsigned short* __restrict__ gwhi,
                                                const unsigned short* __restrict__ gwlo,
                                                const float* __restrict__ dinv,
                                                __half* __restrict__ T, int nrows) {
    constexpr int NT = BN / 16;
    constexpr int WFRAG = 4 * NT * 64 * 8;
    __shared__ __align__(16) unsigned short s_hi[WFRAG];
    __shared__ __align__(16) unsigned short s_lo[WFRAG];
    int tid = threadIdx.x;
    for (int i = tid; i < WFRAG / 8; i += 256) {
        ((uint4*)s_hi)[i] = ((const uint4*)gwhi)[i];
        ((uint4*)s_lo)[i] = ((const uint4*)gwlo)[i];
    }
    __syncthreads();

    int wave = tid >> 6, lane = tid & 63;
    int m = lane & 15, q = lane >> 4;
    long row0 = ((long)blockIdx.x * 4 + wave) * 32;
    if (row0 >= nrows) return;
    long rowa = row0 + m;
    bool hasb = (row0 + 16) < nrows;
    long rowb = hasb ? (row0 + 16 + m) : rowa;

    f32x4 acc[2][NT];
#pragma unroll
    for (int s = 0; s < 2; s++)
#pragma unroll
        for (int t = 0; t < NT; t++)
#pragma unroll
            for (int r = 0; r < 4; r++) acc[s][t][r] = 0.f;

#pragma unroll
    for (int c = 0; c < 4; c++) {
        f16x8 a[2];
        *(uint4*)&a[0] = *(const uint4*)(A + rowa * 128 + c * 32 + q * 8);
        *(uint4*)&a[1] = *(const uint4*)(A + rowb * 128 + c * 32 + q * 8);
#pragma unroll
        for (int t = 0; t < NT; t++) {
            f16x8 bhi = *(const f16x8*)(s_hi + ((c * NT + t) * 64 + lane) * 8);
            f16x8 blo = *(const f16x8*)(s_lo + ((c * NT + t) * 64 + lane) * 8);
#pragma unroll
            for (int s = 0; s < 2; s++) {
                acc[s][t] = __builtin_amdgcn_mfma_f32_16x16x32_f16(a[s], blo, acc[s][t], 0, 0, 0);
                acc[s][t] = __builtin_amdgcn_mfma_f32_16x16x32_f16(a[s], bhi, acc[s][t], 0, 0, 0);
            }
        }
    }

#pragma unroll
    for (int s = 0; s < 2; s++) {
        if (s == 1 && !hasb) break;
#pragma unroll
        for (int r = 0; r < 4; r++) {
            long row = row0 + s * 16 + q * 4 + r;
            if (row < nrows) {
                float di = dinv[row];
#pragma unroll
                for (int t = 0; t < NT; t++)
                    T[row * BN + t * 16 + m] = __float2half(acc[s][t][r] * di);
            }
        }
    }
}

// ---------------- aggregation: wave per node, quarter-wave per row -------------------
// lane = (q, i): q = lane>>4 edge slot base, i = lane&15 (16B of the 256B row).
// Uniform masked 32-edge loop: 8 independent uint4 gathers in flight.

__global__ __launch_bounds__(256) void agg128h(const __half* __restrict__ t,
                                               const int* __restrict__ row_ptr,
                                               const int* __restrict__ col,
                                               const float* __restrict__ dinv,
                                               const float* __restrict__ bias,
                                               __half* __restrict__ out, int n) {
    int wave = threadIdx.x >> 6, lane = threadIdx.x & 63;
    int node = blockIdx.x * 4 + wave;
    if (node >= n) return;
    int q = lane >> 4, i = lane & 15;
    int r0 = row_ptr[node], r1 = row_ptr[node + 1];
    const uint4* t4 = (const uint4*)t;

    float a0[8], a1[8], a2[8], a3[8];
#pragma unroll
    for (int k = 0; k < 8; k++) { a0[k] = 0.f; a1[k] = 0.f; a2[k] = 0.f; a3[k] = 0.f; }

    for (int p = r0; p < r1; p += 32) {
        int idx[8]; int c[8]; float mk[8];
#pragma unroll
        for (int s = 0; s < 8; s++) {
            idx[s] = p + s * 4 + q;
            bool v = idx[s] < r1;
            int safe = v ? idx[s] : r0;
            c[s] = col[safe];
            mk[s] = v ? 1.f : 0.f;
        }
        uint4 g0 = t4[(size_t)c[0] * 16 + i];
        uint4 g1 = t4[(size_t)c[1] * 16 + i];
        uint4 g2 = t4[(size_t)c[2] * 16 + i];
        uint4 g3 = t4[(size_t)c[3] * 16 + i];
        uint4 g4 = t4[(size_t)c[4] * 16 + i];
        uint4 g5 = t4[(size_t)c[5] * 16 + i];
        uint4 g6 = t4[(size_t)c[6] * 16 + i];
        uint4 g7 = t4[(size_t)c[7] * 16 + i];
        accm8(a0, g0, mk[0]); accm8(a1, g1, mk[1]);
        accm8(a2, g2, mk[2]); accm8(a3, g3, mk[3]);
        accm8(a0, g4, mk[4]); accm8(a1, g5, mk[5]);
        accm8(a2, g6, mk[6]); accm8(a3, g7, mk[7]);
    }

    float s[8];
#pragma unroll
    for (int k = 0; k < 8; k++) s[k] = (a0[k] + a1[k]) + (a2[k] + a3[k]);
#pragma unroll
    for (int k = 0; k < 8; k++) s[k] += __shfl_xor(s[k], 16);
#pragma unroll
    for (int k = 0; k < 8; k++) s[k] += __shfl_xor(s[k], 32);

    if (q == 0) {
        uint4 ownv = t4[(size_t)node * 16 + i];
        float own[8];
        float2 f0 = h2f2(ownv.x), f1 = h2f2(ownv.y), f2 = h2f2(ownv.z), f3 = h2f2(ownv.w);
        own[0] = f0.x; own[1] = f0.y; own[2] = f1.x; own[3] = f1.y;
        own[4] = f2.x; own[5] = f2.y; own[6] = f3.x; own[7] = f3.y;
        float di = dinv[node];
        float4 bA = ((const float4*)bias)[i * 2];
        float4 bB = ((const float4*)bias)[i * 2 + 1];
        float o[8];
        o[0] = fmaf(di, s[0] + own[0], bA.x);
        o[1] = fmaf(di, s[1] + own[1], bA.y);
        o[2] = fmaf(di, s[2] + own[2], bA.z);
        o[3] = fmaf(di, s[3] + own[3], bA.w);
        o[4] = fmaf(di, s[4] + own[4], bB.x);
        o[5] = fmaf(di, s[5] + own[5], bB.y);
        o[6] = fmaf(di, s[6] + own[6], bB.z);
        o[7] = fmaf(di, s[7] + own[7], bB.w);
#pragma unroll
        for (int k = 0; k < 8; k++) o[k] = fmaxf(o[k], 0.f);
        uint4 ov;
        ov.x = f22h2(o[0], o[1]); ov.y = f22h2(o[2], o[3]);
        ov.z = f22h2(o[4], o[5]); ov.w = f22h2(o[6], o[7]);
        ((uint4*)out)[(size_t)node * 16 + i] = ov;
    }
}

// 64-feature final layer: fp16 table uint2/lane, fp32 row-major out, no relu.
__global__ __launch_bounds__(256) void agg64h(const __half* __restrict__ t,
                                              const int* __restrict__ row_ptr,
                                              const int* __restrict__ col,
                                              const float* __restrict__ dinv,
                                              const float* __restrict__ bias,
                                              float* __restrict__ out, int n) {
    int wave = threadIdx.x >> 6, lane = threadIdx.x & 63;
    int node = blockIdx.x * 4 + wave;
    if (node >= n) return;
    int q = lane >> 4, i = lane & 15;
    int r0 = row_ptr[node], r1 = row_ptr[node + 1];
    const uint2* t2 = (const uint2*)t;

    float a0[4], a1[4], a2[4], a3[4];
#pragma unroll
    for (int k = 0; k < 4; k++) { a0[k] = 0.f; a1[k] = 0.f; a2[k] = 0.f; a3[k] = 0.f; }

    for (int p = r0; p < r1; p += 32) {
        int idx[8]; int c[8]; float mk[8];
#pragma unroll
        for (int s = 0; s < 8; s++) {
            idx[s] = p + s * 4 + q;
            bool v = idx[s] < r1;
            int safe = v ? idx[s] : r0;
            c[s] = col[safe];
            mk[s] = v ? 1.f : 0.f;
        }
        uint2 g0 = t2[(size_t)c[0] * 16 + i];
        uint2 g1 = t2[(size_t)c[1] * 16 + i];
        uint2 g2 = t2[(size_t)c[2] * 16 + i];
        uint2 g3 = t2[(size_t)c[3] * 16 + i];
        uint2 g4 = t2[(size_t)c[4] * 16 + i];
        uint2 g5 = t2[(size_t)c[5] * 16 + i];
        uint2 g6 = t2[(size_t)c[6] * 16 + i];
        uint2 g7 = t2[(size_t)c[7] * 16 + i];
        accm4(a0, g0, mk[0]); accm4(a1, g1, mk[1]);
        accm4(a2, g2, mk[2]); accm4(a3, g3, mk[3]);
        accm4(a0, g4, mk[4]); accm4(a1, g5, mk[5]);
        accm4(a2, g6, mk[6]); accm4(a3, g7, mk[7]);
    }

    float s[4];
#pragma unroll
    for (int k = 0; k < 4; k++) s[k] = (a0[k] + a1[k]) + (a2[k] + a3[k]);
#pragma unroll
    for (int k = 0; k < 4; k++) s[k] += __shfl_xor(s[k], 16);
#pragma unroll
    for (int k = 0; k < 4; k++) s[k] += __shfl_xor(s[k], 32);

    if (q == 0) {
        uint2 ownv = t2[(size_t)node * 16 + i];
        float own[4];
        float2 f0 = h2f2(ownv.x), f1 = h2f2(ownv.y);
        own[0] = f0.x; own[1] = f0.y; own[2] = f1.x; own[3] = f1.y;
        float di = dinv[node];
        float4 b4 = ((const float4*)bias)[i];
        float4 o;
        o.x = fmaf(di, s[0] + own[0], b4.x);
        o.y = fmaf(di, s[1] + own[1], b4.y);
        o.z = fmaf(di, s[2] + own[2], b4.z);
        o.w = fmaf(di, s[3] + own[3], b4.w);
        *(float4*)(out + (size_t)node * 64 + i * 4) = o;
    }
}

// ---------------- launch ----------------

extern "C" void kernel_launch(void* const* d_in, const int* in_sizes, int n_in,
                              void* d_out, int out_size, void* d_ws, size_t ws_size,
                              hipStream_t stream) {
    const int N = NNODES, E = NEDGES;
    const float* x   = (const float*)d_in[0];
    const int*   ei  = (const int*)d_in[1];
    const int*   src = ei;
    const int*   dst = ei + E;
    const float* W1  = (const float*)d_in[2];
    const float* b1  = (const float*)d_in[3];
    const float* Wm1 = (const float*)d_in[4];
    const float* bm1 = (const float*)d_in[5];
    const float* Wm2 = (const float*)d_in[6];
    const float* bm2 = (const float*)d_in[7];
    const float* W2  = (const float*)d_in[8];
    const float* b2  = (const float*)d_in[9];
    float* out = (float*)d_out;

    // workspace layout (16B-aligned segments)
    int* bucket_cnt  = (int*)d_ws;                        // 784
    int* bucket_base = bucket_cnt + 784;                  // 784 (NBUCK+1 used)
    int* bucket_fill = bucket_base + 784;                 // 784
    int* row_ptr     = bucket_fill + 784;                 // N+4
    int* col         = row_ptr + (N + 4);                 // E
    unsigned int* epart = (unsigned int*)(col + E);       // E
    float* dinv  = (float*)(epart + E);                   // N
    __half* t16  = (__half*)(dinv + N);                   // N*128 halves
    __half* bufA = t16 + (size_t)N * 128;                 // N*128 halves
    unsigned short* whi1  = (unsigned short*)(bufA + (size_t)N * 128);
    unsigned short* wlo1  = whi1 + 16384;
    unsigned short* whiM1 = wlo1 + 16384;
    unsigned short* wloM1 = whiM1 + 16384;
    unsigned short* whiM2 = wloM1 + 16384;
    unsigned short* wloM2 = whiM2 + 16384;
    unsigned short* whi2  = wloM2 + 16384;
    unsigned short* wlo2  = whi2 + 8192;

    const int EB4 = (E + 4095) / 4096;   // 391

    zero_ints<<<4, 256, 0, stream>>>(bucket_cnt, NBUCK);
    hist_pass<<<EB4, 256, 0, stream>>>(dst, bucket_cnt, E);
    aux_kernel<<<225, 256, 0, stream>>>(W1, whi1, wlo1, Wm1, whiM1, wloM1,
                                        Wm2, whiM2, wloM2, W2, whi2, wlo2,
                                        bucket_cnt, bucket_base, E);
    copy_fill<<<4, 256, 0, stream>>>(bucket_base, bucket_fill);
    scatter_pass<<<EB4, 256, 0, stream>>>(src, dst, bucket_fill, epart, E);
    build_csr<<<NBUCK, 256, 0, stream>>>(epart, bucket_base, row_ptr, col, dinv, N, E);

    const int GB = (N + 127) / 128;      // gemm: 32 rows/wave * 4 waves
    const int AB = (N + 3) / 4;          // agg: 4 nodes/block

    gemm_l1<<<GB, 256, 0, stream>>>(x, whi1, wlo1, dinv, t16, N);
    agg128h<<<AB, 256, 0, stream>>>(t16, row_ptr, col, dinv, b1, bufA, N);

    gemm_f16<128><<<GB, 256, 0, stream>>>(bufA, whiM1, wloM1, dinv, t16, N);
    agg128h<<<AB, 256, 0, stream>>>(t16, row_ptr, col, dinv, bm1, bufA, N);

    gemm_f16<128><<<GB, 256, 0, stream>>>(bufA, whiM2, wloM2, dinv, t16, N);
    agg128h<<<AB, 256, 0, stream>>>(t16, row_ptr, col, dinv, bm2, bufA, N);

    gemm_f16<64><<<GB, 256, 0, stream>>>(bufA, whi2, wlo2, dinv, t16, N);
    agg64h<<<AB, 256, 0, stream>>>(t16, row_ptr, col, dinv, b2, out, N);
}